// Round 2
// baseline (328.635 us; speedup 1.0000x reference)
//
#include <hip/hip_runtime.h>
#include <hip/hip_cooperative_groups.h>
#include <hip/hip_bf16.h>
#include <math.h>

namespace cg = cooperative_groups;

#define T_TRACKS 1024
#define HIDDEN 128
#define LATENT 16
#define NGRID 16
#define NCELLS 256
#define KDIM 4096
#define OUTD 128

typedef unsigned short ushort_t;
typedef __attribute__((ext_vector_type(8))) short frag_ab;   // 8 bf16
typedef __attribute__((ext_vector_type(4))) float f32x4;

static __device__ inline ushort_t f2bf(float x) {
    __hip_bfloat16 h = __float2bfloat16(x);
    return *reinterpret_cast<ushort_t*>(&h);
}

// ---------------- ws layout (byte offsets) ----------------
// vals_t bf16 [16 l][1024 j]      @ 0         (32 KB)
// owner u16 [1024 i][256 c]       @ 32768     (512 KB)  winner j+1, 0 = empty/invalid
// W_t bf16 [128 o][4096 k]        @ 557056    (1 MB)
// partial f32 [16 kt][1024][128]  @ 1605632   (8 MB)
#define WS_VALS 0
#define WS_OWN  32768
#define WS_WT   557056
#define WS_PART 1605632
#define WS_NEED (1605632 + 8388608)

// ==================== fused cooperative kernel ====================
// grid = 1024 blocks x 256 thr. Co-residency: LDS 39168 B (4x = 156 KB < 160 KB),
// __launch_bounds__(256,4) caps VGPR at 128 -> 16 waves/CU -> 4 blocks/CU -> 1024 resident.
// Phase A: blocks 0..63 vals_t | 64..127 owner | 128..383 W_t transpose.
// Phase B: kt = b>>6 (16 K-segs == one latent each), mt = b&63 (16-row M-tile).
//          Waves split N: wave w handles ntiles {2w, 2w+1}.
// Phase C: first 32768 threads reduce 16 partials + bias + relu.
__global__ __launch_bounds__(256, 4) void fused_kernel(const float* __restrict__ hidden,
                                                       const float* __restrict__ obs2,
                                                       const float* __restrict__ W_enc,
                                                       const float* __restrict__ b_enc,
                                                       const float* __restrict__ W_emb,
                                                       const float* __restrict__ b_emb,
                                                       ushort_t* __restrict__ vals_t,
                                                       ushort_t* __restrict__ owner,
                                                       ushort_t* __restrict__ W_t,
                                                       float* __restrict__ partial,
                                                       float* __restrict__ out) {
    cg::grid_group grid = cg::this_grid();
    const int b = blockIdx.x;
    const int tid = threadIdx.x;

    // 39168 B: phase A owner view = sobs f32x2[1024] (8192) + own int[16][256] (16384) = 24576
    //          phase B view       = As u16[16][136] (4352) + Bs u16[128][136] (34816) = 39168
    __shared__ __attribute__((aligned(16))) char smem_raw[39168];

    // ---------------- Phase A ----------------
    if (b < 64) {
        // vals_t[l][j] = bf16(hidden[j] @ W_enc[:,l] + b_enc[l])
        int idx = b * 256 + tid;           // 0..16383
        int j = idx >> 4, l = idx & 15;
        const float* h = hidden + j * HIDDEN;
        float acc = b_enc[l];
#pragma unroll 8
        for (int k = 0; k < HIDDEN; k++) acc += h[k] * W_enc[k * LATENT + l];
        vals_t[l * T_TRACKS + j] = f2bf(acc);
    } else if (b < 128) {
        // owner map for 16 rows (winner = max j; ref's .set is last-write = max j)
        float2* sobs = reinterpret_cast<float2*>(smem_raw);          // 8 KB
        int* own = reinterpret_cast<int*>(smem_raw + 8192);          // [16][256], 16 KB
        const int rbase = (b - 64) * 16;
        for (int q = tid; q < T_TRACKS; q += 256) {
            float2 o = reinterpret_cast<const float2*>(obs2)[q];
            if (isnan(o.x) || isnan(o.y)) { o.x = 0.0f; o.y = 0.0f; }
            sobs[q] = o;
        }
        for (int q = tid; q < 16 * NCELLS; q += 256) own[q] = -1;
        __syncthreads();
        {
            const int r = tid & 15;
            const int i = rbase + r;
            const float oix = sobs[i].x, oiy = sobs[i].y;
            for (int j = tid >> 4; j < T_TRACKS; j += 16) {
                if (j == i) continue;
                float gx = (sobs[j].x - oix) * 0.5f + 8.0f;
                float gy = (sobs[j].y - oiy) * 0.5f + 8.0f;
                bool inr = (gx >= 0.0f) && (gx < 16.0f) && (gy >= 0.0f) && (gy < 16.0f);
                int c = inr ? ((int)gx * NGRID + (int)gy) : 0;  // OOR scatters 0 into cell 0
                atomicMax(&own[r * NCELLS + c], j);
            }
        }
        __syncthreads();
        for (int q = tid; q < 16 * NCELLS; q += 256) {
            int rr = q >> 8, c = q & 255;
            int j = own[q];
            bool valid = (j >= 0);
            if (valid && c == 0) {
                // cell 0's winner may be an out-of-range neighbor (scatters value 0 in ref)
                float oix = sobs[rbase + rr].x, oiy = sobs[rbase + rr].y;
                float gx = (sobs[j].x - oix) * 0.5f + 8.0f;
                float gy = (sobs[j].y - oiy) * 0.5f + 8.0f;
                valid = (gx >= 0.0f) && (gx < 16.0f) && (gy >= 0.0f) && (gy < 16.0f);
            }
            owner[(rbase + rr) * NCELLS + c] = valid ? (ushort_t)(j + 1) : (ushort_t)0;
        }
    } else {
        // W_t[o][k] = bf16(W_emb[k][o]) ; 65536 octet-items over blocks 128..383
        int idx = (b - 128) * 256 + tid;
        if (idx < 65536) {
            int kc = idx >> 7, o = idx & 127;
            ushort_t tmp[8];
#pragma unroll
            for (int u = 0; u < 8; u++) tmp[u] = f2bf(W_emb[(kc * 8 + u) * OUTD + o]);
            *reinterpret_cast<uint4*>(W_t + o * KDIM + kc * 8) = *reinterpret_cast<uint4*>(tmp);
        }
    }

    grid.sync();

    // ---------------- Phase B: GEMM ----------------
    {
        const int kt = b >> 6;       // 0..15  (K-seg == latent kt)
        const int mt = b & 63;       // 0..63  (rows mt*16 .. +16)
        const int wave = tid >> 6;
        const int lane = tid & 63;
        const int lrow = lane & 15;
        const int quad = lane >> 4;

        ushort_t* As = reinterpret_cast<ushort_t*>(smem_raw);               // [16][136]
        ushort_t* Bs = reinterpret_cast<ushort_t*>(smem_raw + 16 * 136 * 2); // [128][136]
        const ushort_t* vrow = vals_t + kt * T_TRACKS;   // 2 KB, L1/L2-resident

        f32x4 acc[2];
        acc[0] = (f32x4){0.f, 0.f, 0.f, 0.f};
        acc[1] = (f32x4){0.f, 0.f, 0.f, 0.f};

        for (int chunk = 0; chunk < 2; chunk++) {
            const int c0 = chunk * 128;
            // A: 16 rows x 128 cells = 512 ushort4-quads, 2/thread (gather from owner+vrow)
            for (int q = tid; q < 512; q += 256) {
                int r = q >> 5, c4 = (q & 31) * 4;
                ushort4 o4 = *reinterpret_cast<const ushort4*>(owner + (mt * 16 + r) * NCELLS + c0 + c4);
                ushort4 v;
                v.x = o4.x ? vrow[o4.x - 1] : (ushort_t)0;
                v.y = o4.y ? vrow[o4.y - 1] : (ushort_t)0;
                v.z = o4.z ? vrow[o4.z - 1] : (ushort_t)0;
                v.w = o4.w ? vrow[o4.w - 1] : (ushort_t)0;
                *reinterpret_cast<ushort4*>(As + r * 136 + c4) = v;
            }
            // B: 128 n-rows x 128 k = 2048 16B-granules, 8/thread
            for (int g = tid; g < 2048; g += 256) {
                int n = g >> 4, cs = g & 15;
                uint4 v = *reinterpret_cast<const uint4*>(W_t + n * KDIM + kt * 256 + c0 + cs * 8);
                *reinterpret_cast<uint4*>(Bs + n * 136 + cs * 8) = v;
            }
            __syncthreads();
#pragma unroll
            for (int ks = 0; ks < 4; ks++) {   // K=32 per mfma
                const int koff = ks * 32 + quad * 8;
                frag_ab a = *reinterpret_cast<const frag_ab*>(&As[lrow * 136 + koff]);
#pragma unroll
                for (int nt2 = 0; nt2 < 2; nt2++) {
                    int nrow = (wave * 2 + nt2) * 16 + lrow;
                    frag_ab bfr = *reinterpret_cast<const frag_ab*>(&Bs[nrow * 136 + koff]);
                    acc[nt2] = __builtin_amdgcn_mfma_f32_16x16x32_bf16(a, bfr, acc[nt2], 0, 0, 0);
                }
            }
            __syncthreads();
        }
        // C/D layout: col = lane&15, row = quad*4+reg (m89/m91-verified)
        float* pt = partial + (size_t)kt * (T_TRACKS * OUTD) + (mt * 16) * OUTD;
#pragma unroll
        for (int nt2 = 0; nt2 < 2; nt2++) {
            int n = (wave * 2 + nt2) * 16 + lrow;
#pragma unroll
            for (int reg = 0; reg < 4; reg++) {
                int m = quad * 4 + reg;
                pt[m * OUTD + n] = acc[nt2][reg];
            }
        }
    }

    grid.sync();

    // ---------------- Phase C: reduce + bias + relu ----------------
    {
        int gid = b * 256 + tid;
        if (gid < 32768) {   // [1024][128] in float4 groups
            const float4* p4 = reinterpret_cast<const float4*>(partial);
            float4 s = p4[gid];
#pragma unroll
            for (int kt = 1; kt < 16; kt++) {
                float4 v = p4[kt * 32768 + gid];
                s.x += v.x; s.y += v.y; s.z += v.z; s.w += v.w;
            }
            float4 bv = reinterpret_cast<const float4*>(b_emb)[gid & 31];
            float4 r;
            r.x = fmaxf(s.x + bv.x, 0.0f);
            r.y = fmaxf(s.y + bv.y, 0.0f);
            r.z = fmaxf(s.z + bv.z, 0.0f);
            r.w = fmaxf(s.w + bv.w, 0.0f);
            reinterpret_cast<float4*>(out)[gid] = r;
        }
    }
}

// ==================== non-cooperative fallback (round-1 verified) ====================
__global__ __launch_bounds__(256) void prep_kernel(const float* __restrict__ hidden,
                                                   const float* __restrict__ obs2,
                                                   const float* __restrict__ W_enc,
                                                   const float* __restrict__ b_enc,
                                                   const float* __restrict__ W_emb,
                                                   ushort_t* __restrict__ vals_t,
                                                   ushort_t* __restrict__ owner,
                                                   ushort_t* __restrict__ W_t) {
    const int b = blockIdx.x;
    const int tid = threadIdx.x;
    if (b < 64) {
        int idx = b * 256 + tid;
        int j = idx >> 4, l = idx & 15;
        const float* h = hidden + j * HIDDEN;
        float acc = b_enc[l];
#pragma unroll 8
        for (int k = 0; k < HIDDEN; k++) acc += h[k] * W_enc[k * LATENT + l];
        vals_t[l * T_TRACKS + j] = f2bf(acc);
    } else if (b < 320) {
        int idx = (b - 64) * 256 + tid;
        int kc = idx >> 7;
        int o = idx & 127;
        ushort_t tmp[8];
#pragma unroll
        for (int u = 0; u < 8; u++) tmp[u] = f2bf(W_emb[(kc * 8 + u) * OUTD + o]);
        *reinterpret_cast<uint4*>(W_t + o * KDIM + kc * 8) = *reinterpret_cast<uint4*>(tmp);
    } else {
        __shared__ float2 sobs[T_TRACKS];
        __shared__ int own[16][NCELLS];
        const int rbase = (b - 320) * 16;
        for (int q = tid; q < T_TRACKS; q += 256) {
            float2 o = reinterpret_cast<const float2*>(obs2)[q];
            if (isnan(o.x) || isnan(o.y)) { o.x = 0.0f; o.y = 0.0f; }
            sobs[q] = o;
        }
        for (int q = tid; q < 16 * NCELLS; q += 256) (&own[0][0])[q] = -1;
        __syncthreads();
        {
            const int r = tid & 15;
            const int i = rbase + r;
            const float oix = sobs[i].x, oiy = sobs[i].y;
            for (int j = tid >> 4; j < T_TRACKS; j += 16) {
                if (j == i) continue;
                float gx = (sobs[j].x - oix) * 0.5f + 8.0f;
                float gy = (sobs[j].y - oiy) * 0.5f + 8.0f;
                bool inr = (gx >= 0.0f) && (gx < 16.0f) && (gy >= 0.0f) && (gy < 16.0f);
                int c = inr ? ((int)gx * NGRID + (int)gy) : 0;
                atomicMax(&own[r][c], j);
            }
        }
        __syncthreads();
        for (int q = tid; q < 16 * NCELLS; q += 256) {
            int rr = q >> 8, c = q & 255;
            int j = own[rr][c];
            bool valid = (j >= 0);
            if (valid && c == 0) {
                float oix = sobs[rbase + rr].x, oiy = sobs[rbase + rr].y;
                float gx = (sobs[j].x - oix) * 0.5f + 8.0f;
                float gy = (sobs[j].y - oiy) * 0.5f + 8.0f;
                valid = (gx >= 0.0f) && (gx < 16.0f) && (gy >= 0.0f) && (gy < 16.0f);
            }
            owner[(rbase + rr) * NCELLS + c] = valid ? (ushort_t)(j + 1) : (ushort_t)0;
        }
    }
}

#define LDSTR 136
__global__ __launch_bounds__(256) void gemm_kernel(const ushort_t* __restrict__ owner,
                                                   const ushort_t* __restrict__ vals_t,
                                                   const ushort_t* __restrict__ W_t,
                                                   float* __restrict__ partial) {
    const int tid = threadIdx.x;
    const int kt = blockIdx.x >> 4;
    const int mt = blockIdx.x & 15;
    const int wave = tid >> 6;
    const int lane = tid & 63;
    const int lrow = lane & 15;
    const int quad = lane >> 4;

    __shared__ ushort_t As[64 * LDSTR];
    __shared__ ushort_t Bs[128 * LDSTR];

    const ushort_t* vrow = vals_t + kt * T_TRACKS;

    f32x4 acc[8];
#pragma unroll
    for (int nt = 0; nt < 8; nt++) acc[nt] = (f32x4){0.f, 0.f, 0.f, 0.f};

    for (int chunk = 0; chunk < 2; chunk++) {
        const int c0 = chunk * 128;
        for (int q = tid; q < 2048; q += 256) {
            int r = q >> 5, c4 = (q & 31) * 4;
            ushort4 o4 = *reinterpret_cast<const ushort4*>(owner + (mt * 64 + r) * NCELLS + c0 + c4);
            ushort4 v;
            v.x = o4.x ? vrow[o4.x - 1] : (ushort_t)0;
            v.y = o4.y ? vrow[o4.y - 1] : (ushort_t)0;
            v.z = o4.z ? vrow[o4.z - 1] : (ushort_t)0;
            v.w = o4.w ? vrow[o4.w - 1] : (ushort_t)0;
            *reinterpret_cast<ushort4*>(As + r * LDSTR + c4) = v;
        }
        for (int g = tid; g < 2048; g += 256) {
            int n = g >> 4, cs = g & 15;
            uint4 v = *reinterpret_cast<const uint4*>(W_t + n * KDIM + kt * 256 + c0 + cs * 8);
            *reinterpret_cast<uint4*>(Bs + n * LDSTR + cs * 8) = v;
        }
        __syncthreads();
#pragma unroll
        for (int ks = 0; ks < 4; ks++) {
            const int koff = ks * 32 + quad * 8;
            frag_ab a = *reinterpret_cast<const frag_ab*>(&As[(wave * 16 + lrow) * LDSTR + koff]);
#pragma unroll
            for (int nt = 0; nt < 8; nt++) {
                frag_ab bfr = *reinterpret_cast<const frag_ab*>(&Bs[(nt * 16 + lrow) * LDSTR + koff]);
                acc[nt] = __builtin_amdgcn_mfma_f32_16x16x32_bf16(a, bfr, acc[nt], 0, 0, 0);
            }
        }
        __syncthreads();
    }
    float* pt = partial + (size_t)kt * (T_TRACKS * OUTD) + (mt * 64) * OUTD;
#pragma unroll
    for (int nt = 0; nt < 8; nt++) {
        int n = nt * 16 + lrow;
#pragma unroll
        for (int reg = 0; reg < 4; reg++) {
            int m = wave * 16 + quad * 4 + reg;
            pt[m * OUTD + n] = acc[nt][reg];
        }
    }
}

__global__ __launch_bounds__(256) void reduce_kernel(const float* __restrict__ partial,
                                                     const float* __restrict__ b_emb,
                                                     float* __restrict__ out) {
    int idx = blockIdx.x * 256 + threadIdx.x;
    const float4* p4 = reinterpret_cast<const float4*>(partial);
    float4 s = p4[idx];
#pragma unroll
    for (int kt = 1; kt < 16; kt++) {
        float4 v = p4[kt * 32768 + idx];
        s.x += v.x; s.y += v.y; s.z += v.z; s.w += v.w;
    }
    float4 bv = reinterpret_cast<const float4*>(b_emb)[idx & 31];
    float4 r;
    r.x = fmaxf(s.x + bv.x, 0.0f);
    r.y = fmaxf(s.y + bv.y, 0.0f);
    r.z = fmaxf(s.z + bv.z, 0.0f);
    r.w = fmaxf(s.w + bv.w, 0.0f);
    reinterpret_cast<float4*>(out)[idx] = r;
}

// ================= tiny-ws fallback (f32, fused) =================
__global__ __launch_bounds__(256) void vals_kernel_f32(const float* __restrict__ hidden,
                                                       const float* __restrict__ W_enc,
                                                       const float* __restrict__ b_enc,
                                                       float* __restrict__ vals) {
    int idx = blockIdx.x * 256 + threadIdx.x;
    int j = idx >> 4, l = idx & 15;
    const float* h = hidden + j * HIDDEN;
    float acc = b_enc[l];
#pragma unroll 8
    for (int k = 0; k < HIDDEN; k++) acc += h[k] * W_enc[k * LATENT + l];
    vals[idx] = acc;
}

__global__ __launch_bounds__(256) void pool_kernel_f32(const float* __restrict__ obs2,
                                                       const float* __restrict__ vals,
                                                       const float* __restrict__ W_emb,
                                                       const float* __restrict__ b_emb,
                                                       float* __restrict__ out) {
    const int i = blockIdx.x;
    const int tid = threadIdx.x;
    __shared__ int owner[NCELLS];
    __shared__ float occ[NCELLS * LATENT];
    __shared__ float partial[OUTD];
    owner[tid] = -1;
    float oix = obs2[i * 2 + 0];
    float oiy = obs2[i * 2 + 1];
    if (isnan(oix) || isnan(oiy)) { oix = 0.0f; oiy = 0.0f; }
    __syncthreads();
    for (int j = tid; j < T_TRACKS; j += 256) {
        if (j == i) continue;
        float ox = obs2[j * 2 + 0], oy = obs2[j * 2 + 1];
        if (isnan(ox) || isnan(oy)) { ox = 0.0f; oy = 0.0f; }
        float gx = (ox - oix) * 0.5f + 8.0f;
        float gy = (oy - oiy) * 0.5f + 8.0f;
        bool inr = (gx >= 0.0f) && (gx < 16.0f) && (gy >= 0.0f) && (gy < 16.0f);
        int c = inr ? ((int)gx * NGRID + (int)gy) : 0;
        atomicMax(&owner[c], j);
    }
    __syncthreads();
    {
        int j = owner[tid];
        bool valid = false;
        if (j >= 0) {
            float ox = obs2[j * 2 + 0], oy = obs2[j * 2 + 1];
            if (isnan(ox) || isnan(oy)) { ox = 0.0f; oy = 0.0f; }
            float gx = (ox - oix) * 0.5f + 8.0f;
            float gy = (oy - oiy) * 0.5f + 8.0f;
            valid = (gx >= 0.0f) && (gx < 16.0f) && (gy >= 0.0f) && (gy < 16.0f);
        }
        const float* vj = vals + (j >= 0 ? j : 0) * LATENT;
#pragma unroll
        for (int l = 0; l < LATENT; l++) occ[tid * LATENT + l] = valid ? vj[l] : 0.0f;
    }
    __syncthreads();
    const int o = tid & (OUTD - 1);
    const int half = tid >> 7;
    const int cbase = half * 128;
    float acc = 0.0f;
    for (int c = cbase; c < cbase + 128; c++) {
#pragma unroll
        for (int l = 0; l < LATENT; l++)
            acc += occ[c * LATENT + l] * W_emb[(l * NCELLS + c) * OUTD + o];
    }
    if (half == 0) partial[o] = acc;
    __syncthreads();
    if (half == 1) out[i * OUTD + o] = fmaxf(acc + partial[o] + b_emb[o], 0.0f);
}

extern "C" void kernel_launch(void* const* d_in, const int* in_sizes, int n_in,
                              void* d_out, int out_size, void* d_ws, size_t ws_size,
                              hipStream_t stream) {
    const float* hidden = (const float*)d_in[0];   // [1024,128]
    const float* obs2   = (const float*)d_in[2];   // [1024,2]
    const float* W_enc  = (const float*)d_in[3];   // [128,16]
    const float* b_enc  = (const float*)d_in[4];   // [16]
    const float* W_emb  = (const float*)d_in[5];   // [4096,128]
    const float* b_emb  = (const float*)d_in[6];   // [128]
    float* out = (float*)d_out;                    // [1024,128]

    if (ws_size < (size_t)WS_NEED) {
        float* vals = (float*)d_ws;
        vals_kernel_f32<<<(T_TRACKS * LATENT) / 256, 256, 0, stream>>>(hidden, W_enc, b_enc, vals);
        pool_kernel_f32<<<T_TRACKS, 256, 0, stream>>>(obs2, vals, W_emb, b_emb, out);
        return;
    }

    char* ws = (char*)d_ws;
    ushort_t* vals_t  = (ushort_t*)(ws + WS_VALS);
    ushort_t* owner   = (ushort_t*)(ws + WS_OWN);
    ushort_t* W_t     = (ushort_t*)(ws + WS_WT);
    float*    partial = (float*)(ws + WS_PART);

    void* args[] = {(void*)&hidden, (void*)&obs2, (void*)&W_enc, (void*)&b_enc,
                    (void*)&W_emb, (void*)&b_emb,
                    (void*)&vals_t, (void*)&owner, (void*)&W_t, (void*)&partial, (void*)&out};
    hipError_t err = hipLaunchCooperativeKernel((void*)fused_kernel, dim3(1024), dim3(256),
                                                args, 0, stream);
    if (err == hipSuccess) return;

    // cooperative launch rejected -> verified 3-kernel path
    prep_kernel<<<384, 256, 0, stream>>>(hidden, obs2, W_enc, b_enc, W_emb, vals_t, owner, W_t);
    gemm_kernel<<<256, 256, 0, stream>>>(owner, vals_t, W_t, partial);
    reduce_kernel<<<128, 256, 0, stream>>>(partial, b_emb, out);
}

// Round 3
// 193.641 us; speedup vs baseline: 1.6971x; 1.6971x over previous
//
#include <hip/hip_runtime.h>
#include <hip/hip_bf16.h>
#include <math.h>

#define T_TRACKS 1024
#define HIDDEN 128
#define LATENT 16
#define NGRID 16
#define NCELLS 256
#define KDIM 4096
#define OUTD 128

typedef unsigned short ushort_t;
typedef __attribute__((ext_vector_type(8))) short frag_ab;   // 8 bf16
typedef __attribute__((ext_vector_type(4))) float f32x4;

static __device__ inline ushort_t f2bf(float x) {
    __hip_bfloat16 h = __float2bfloat16(x);
    return *reinterpret_cast<ushort_t*>(&h);
}

// ---------------- ws layout (byte offsets) ----------------
// vals_t bf16 [16 l][1024 j]      @ 0         (32 KB)
// owner u16 [1024 i][256 c]       @ 32768     (512 KB)  winner j+1, 0 = empty/invalid
// W_t bf16 [128 o][4096 k]        @ 557056    (1 MB)
// cnt int [64]                    @ 1605632   (256 B)   tile-completion counters
// partial f32 [16 kt][1024][128]  @ 1605888   (8 MB)
#define WS_VALS 0
#define WS_OWN  32768
#define WS_WT   557056
#define WS_CNT  1605632
#define WS_PART 1605888
#define WS_NEED (1605888 + 8388608)

// ============ K1: fused prep (vals_t | W_t transpose | owner map | cnt=0) ============
// verified logic (rounds 1-2); block 0 additionally zeroes the 64 tile counters.
__global__ __launch_bounds__(256) void prep_kernel(const float* __restrict__ hidden,
                                                   const float* __restrict__ obs2,
                                                   const float* __restrict__ W_enc,
                                                   const float* __restrict__ b_enc,
                                                   const float* __restrict__ W_emb,
                                                   ushort_t* __restrict__ vals_t,
                                                   ushort_t* __restrict__ owner,
                                                   ushort_t* __restrict__ W_t,
                                                   int* __restrict__ cnt) {
    const int b = blockIdx.x;
    const int tid = threadIdx.x;
    if (b < 64) {
        if (b == 0 && tid < 64) cnt[tid] = 0;   // ws is re-poisoned every iteration
        // vals_t[l][j] = bf16(hidden[j] @ W_enc[:,l] + b_enc[l])
        int idx = b * 256 + tid;           // 0..16383
        int j = idx >> 4, l = idx & 15;
        const float* h = hidden + j * HIDDEN;
        float acc = b_enc[l];
#pragma unroll 8
        for (int k = 0; k < HIDDEN; k++) acc += h[k] * W_enc[k * LATENT + l];
        vals_t[l * T_TRACKS + j] = f2bf(acc);
    } else if (b < 320) {
        // W_t[o][k] = bf16(W_emb[k][o])
        int idx = (b - 64) * 256 + tid;    // 0..65535
        int kc = idx >> 7;                 // 0..511 (chunk of 8 k)
        int o = idx & 127;
        ushort_t tmp[8];
#pragma unroll
        for (int u = 0; u < 8; u++) tmp[u] = f2bf(W_emb[(kc * 8 + u) * OUTD + o]);
        *reinterpret_cast<uint4*>(W_t + o * KDIM + kc * 8) = *reinterpret_cast<uint4*>(tmp);
    } else {
        // owner map for 16 rows (winner = max j; ref's .set last-write = max j)
        __shared__ float2 sobs[T_TRACKS];      // 8 KB
        __shared__ int own[16][NCELLS];        // 16 KB
        const int rbase = (b - 320) * 16;
        for (int q = tid; q < T_TRACKS; q += 256) {
            float2 o = reinterpret_cast<const float2*>(obs2)[q];
            if (isnan(o.x) || isnan(o.y)) { o.x = 0.0f; o.y = 0.0f; }
            sobs[q] = o;
        }
        for (int q = tid; q < 16 * NCELLS; q += 256) (&own[0][0])[q] = -1;
        __syncthreads();
        {
            const int r = tid & 15;
            const int i = rbase + r;
            const float oix = sobs[i].x, oiy = sobs[i].y;
            for (int j = tid >> 4; j < T_TRACKS; j += 16) {
                if (j == i) continue;
                float gx = (sobs[j].x - oix) * 0.5f + 8.0f;
                float gy = (sobs[j].y - oiy) * 0.5f + 8.0f;
                bool inr = (gx >= 0.0f) && (gx < 16.0f) && (gy >= 0.0f) && (gy < 16.0f);
                int c = inr ? ((int)gx * NGRID + (int)gy) : 0;  // OOR scatters 0 into cell 0
                atomicMax(&own[r][c], j);
            }
        }
        __syncthreads();
        for (int q = tid; q < 16 * NCELLS; q += 256) {
            int rr = q >> 8, c = q & 255;
            int j = own[rr][c];
            bool valid = (j >= 0);
            if (valid && c == 0) {
                // cell 0's winner may be an out-of-range neighbor (value 0 in ref)
                float oix = sobs[rbase + rr].x, oiy = sobs[rbase + rr].y;
                float gx = (sobs[j].x - oix) * 0.5f + 8.0f;
                float gy = (sobs[j].y - oiy) * 0.5f + 8.0f;
                valid = (gx >= 0.0f) && (gx < 16.0f) && (gy >= 0.0f) && (gy < 16.0f);
            }
            owner[(rbase + rr) * NCELLS + c] = valid ? (ushort_t)(j + 1) : (ushort_t)0;
        }
    }
}

// ============ K2: GEMM (1024 blocks, 4/CU) + decoupled tail reduce ============
// kt = b>>6 (consecutive blocks share the W_t slice within an XCD round-robin),
// mt = b&63 (16-row M-tile). Phase-B fragment logic correctness-verified in round 2.
// After writing its partial tile, each block threadfence+atomicAdd(cnt[mt]); the
// 16th arrival reduces all 16 partials + bias + relu for its tile (rocPRIM-style
// decoupled tail; device-scope atomics + fences per Guideline 16).
__global__ __launch_bounds__(256, 4) void gemm_kernel(const ushort_t* __restrict__ owner,
                                                      const ushort_t* __restrict__ vals_t,
                                                      const ushort_t* __restrict__ W_t,
                                                      const float* __restrict__ b_emb,
                                                      float* __restrict__ partial,
                                                      int* __restrict__ cnt,
                                                      float* __restrict__ out) {
    const int tid = threadIdx.x;
    const int kt = blockIdx.x >> 6;    // 0..15 (K-seg == latent kt)
    const int mt = blockIdx.x & 63;    // 0..63 (rows mt*16 .. +16)
    const int wave = tid >> 6;
    const int lane = tid & 63;
    const int lrow = lane & 15;
    const int quad = lane >> 4;

    __shared__ ushort_t As[16 * 136];     // 4352 B
    __shared__ ushort_t Bs[128 * 136];    // 34816 B
    __shared__ int last;                  // tail flag

    const ushort_t* vrow = vals_t + kt * T_TRACKS;   // 2 KB, L1-resident

    f32x4 acc[2];
    acc[0] = (f32x4){0.f, 0.f, 0.f, 0.f};
    acc[1] = (f32x4){0.f, 0.f, 0.f, 0.f};

    for (int chunk = 0; chunk < 2; chunk++) {
        const int c0 = chunk * 128;
        // A: 16 rows x 128 cells = 512 ushort4-quads, 2/thread (gather from owner+vrow)
        for (int q = tid; q < 512; q += 256) {
            int r = q >> 5, c4 = (q & 31) * 4;
            ushort4 o4 = *reinterpret_cast<const ushort4*>(owner + (mt * 16 + r) * NCELLS + c0 + c4);
            ushort4 v;
            v.x = o4.x ? vrow[o4.x - 1] : (ushort_t)0;
            v.y = o4.y ? vrow[o4.y - 1] : (ushort_t)0;
            v.z = o4.z ? vrow[o4.z - 1] : (ushort_t)0;
            v.w = o4.w ? vrow[o4.w - 1] : (ushort_t)0;
            *reinterpret_cast<ushort4*>(As + r * 136 + c4) = v;
        }
        // B: 128 n-rows x 128 k = 2048 16B-granules, 8/thread
        for (int g = tid; g < 2048; g += 256) {
            int n = g >> 4, cs = g & 15;
            uint4 v = *reinterpret_cast<const uint4*>(W_t + n * KDIM + kt * 256 + c0 + cs * 8);
            *reinterpret_cast<uint4*>(Bs + n * 136 + cs * 8) = v;
        }
        __syncthreads();
#pragma unroll
        for (int ks = 0; ks < 4; ks++) {   // K=32 per mfma
            const int koff = ks * 32 + quad * 8;
            frag_ab a = *reinterpret_cast<const frag_ab*>(&As[lrow * 136 + koff]);
#pragma unroll
            for (int nt2 = 0; nt2 < 2; nt2++) {
                int nrow = (wave * 2 + nt2) * 16 + lrow;
                frag_ab bfr = *reinterpret_cast<const frag_ab*>(&Bs[nrow * 136 + koff]);
                acc[nt2] = __builtin_amdgcn_mfma_f32_16x16x32_bf16(a, bfr, acc[nt2], 0, 0, 0);
            }
        }
        __syncthreads();
    }
    // C/D layout: col = lane&15, row = quad*4+reg (m89/m91-verified)
    float* pt = partial + (size_t)kt * (T_TRACKS * OUTD) + (mt * 16) * OUTD;
#pragma unroll
    for (int nt2 = 0; nt2 < 2; nt2++) {
        int n = (wave * 2 + nt2) * 16 + lrow;
#pragma unroll
        for (int reg = 0; reg < 4; reg++) {
            int m = quad * 4 + reg;
            pt[m * OUTD + n] = acc[nt2][reg];
        }
    }

    // ---- decoupled tail: 16th arrival for this mt reduces + bias + relu ----
    __threadfence();                       // release this thread's partial stores
    __syncthreads();                       // all threads of block released
    if (tid == 0) {
        int old = atomicAdd(&cnt[mt], 1);  // device-scope by default
        last = (old == 15);
    }
    __syncthreads();
    if (last) {
        __threadfence();                   // acquire: see all 16 blocks' partials
        const float4* p4 = reinterpret_cast<const float4*>(partial);
        const float4* b4 = reinterpret_cast<const float4*>(b_emb);
        float4* o4 = reinterpret_cast<float4*>(out);
#pragma unroll
        for (int u = 0; u < 2; u++) {
            int e = tid + u * 256;                 // 0..511 float4s in the 16x128 tile
            int base = mt * 512 + e;
            float4 s = p4[base];
#pragma unroll
            for (int k2 = 1; k2 < 16; k2++) {
                float4 v = p4[k2 * 32768 + base];
                s.x += v.x; s.y += v.y; s.z += v.z; s.w += v.w;
            }
            float4 bv = b4[e & 31];
            float4 r;
            r.x = fmaxf(s.x + bv.x, 0.0f);
            r.y = fmaxf(s.y + bv.y, 0.0f);
            r.z = fmaxf(s.z + bv.z, 0.0f);
            r.w = fmaxf(s.w + bv.w, 0.0f);
            o4[base] = r;
        }
    }
}

// ================= tiny-ws fallback (f32, fused, round-1 verified) =================
__global__ __launch_bounds__(256) void vals_kernel_f32(const float* __restrict__ hidden,
                                                       const float* __restrict__ W_enc,
                                                       const float* __restrict__ b_enc,
                                                       float* __restrict__ vals) {
    int idx = blockIdx.x * 256 + threadIdx.x;
    int j = idx >> 4, l = idx & 15;
    const float* h = hidden + j * HIDDEN;
    float acc = b_enc[l];
#pragma unroll 8
    for (int k = 0; k < HIDDEN; k++) acc += h[k] * W_enc[k * LATENT + l];
    vals[idx] = acc;
}

__global__ __launch_bounds__(256) void pool_kernel_f32(const float* __restrict__ obs2,
                                                       const float* __restrict__ vals,
                                                       const float* __restrict__ W_emb,
                                                       const float* __restrict__ b_emb,
                                                       float* __restrict__ out) {
    const int i = blockIdx.x;
    const int tid = threadIdx.x;
    __shared__ int owner[NCELLS];
    __shared__ float occ[NCELLS * LATENT];
    __shared__ float partial[OUTD];
    owner[tid] = -1;
    float oix = obs2[i * 2 + 0];
    float oiy = obs2[i * 2 + 1];
    if (isnan(oix) || isnan(oiy)) { oix = 0.0f; oiy = 0.0f; }
    __syncthreads();
    for (int j = tid; j < T_TRACKS; j += 256) {
        if (j == i) continue;
        float ox = obs2[j * 2 + 0], oy = obs2[j * 2 + 1];
        if (isnan(ox) || isnan(oy)) { ox = 0.0f; oy = 0.0f; }
        float gx = (ox - oix) * 0.5f + 8.0f;
        float gy = (oy - oiy) * 0.5f + 8.0f;
        bool inr = (gx >= 0.0f) && (gx < 16.0f) && (gy >= 0.0f) && (gy < 16.0f);
        int c = inr ? ((int)gx * NGRID + (int)gy) : 0;
        atomicMax(&owner[c], j);
    }
    __syncthreads();
    {
        int j = owner[tid];
        bool valid = false;
        if (j >= 0) {
            float ox = obs2[j * 2 + 0], oy = obs2[j * 2 + 1];
            if (isnan(ox) || isnan(oy)) { ox = 0.0f; oy = 0.0f; }
            float gx = (ox - oix) * 0.5f + 8.0f;
            float gy = (oy - oiy) * 0.5f + 8.0f;
            valid = (gx >= 0.0f) && (gx < 16.0f) && (gy >= 0.0f) && (gy < 16.0f);
        }
        const float* vj = vals + (j >= 0 ? j : 0) * LATENT;
#pragma unroll
        for (int l = 0; l < LATENT; l++) occ[tid * LATENT + l] = valid ? vj[l] : 0.0f;
    }
    __syncthreads();
    const int o = tid & (OUTD - 1);
    const int half = tid >> 7;
    const int cbase = half * 128;
    float acc = 0.0f;
    for (int c = cbase; c < cbase + 128; c++) {
#pragma unroll
        for (int l = 0; l < LATENT; l++)
            acc += occ[c * LATENT + l] * W_emb[(l * NCELLS + c) * OUTD + o];
    }
    if (half == 0) partial[o] = acc;
    __syncthreads();
    if (half == 1) out[i * OUTD + o] = fmaxf(acc + partial[o] + b_emb[o], 0.0f);
}

extern "C" void kernel_launch(void* const* d_in, const int* in_sizes, int n_in,
                              void* d_out, int out_size, void* d_ws, size_t ws_size,
                              hipStream_t stream) {
    const float* hidden = (const float*)d_in[0];   // [1024,128]
    const float* obs2   = (const float*)d_in[2];   // [1024,2]
    const float* W_enc  = (const float*)d_in[3];   // [128,16]
    const float* b_enc  = (const float*)d_in[4];   // [16]
    const float* W_emb  = (const float*)d_in[5];   // [4096,128]
    const float* b_emb  = (const float*)d_in[6];   // [128]
    float* out = (float*)d_out;                    // [1024,128]

    if (ws_size < (size_t)WS_NEED) {
        float* vals = (float*)d_ws;
        vals_kernel_f32<<<(T_TRACKS * LATENT) / 256, 256, 0, stream>>>(hidden, W_enc, b_enc, vals);
        pool_kernel_f32<<<T_TRACKS, 256, 0, stream>>>(obs2, vals, W_emb, b_emb, out);
        return;
    }

    char* ws = (char*)d_ws;
    ushort_t* vals_t  = (ushort_t*)(ws + WS_VALS);
    ushort_t* owner   = (ushort_t*)(ws + WS_OWN);
    ushort_t* W_t     = (ushort_t*)(ws + WS_WT);
    int*      cnt     = (int*)(ws + WS_CNT);
    float*    partial = (float*)(ws + WS_PART);

    prep_kernel<<<384, 256, 0, stream>>>(hidden, obs2, W_enc, b_enc, W_emb,
                                         vals_t, owner, W_t, cnt);
    gemm_kernel<<<1024, 256, 0, stream>>>(owner, vals_t, W_t, b_emb, partial, cnt, out);
}

// Round 4
// 93.859 us; speedup vs baseline: 3.5014x; 2.0631x over previous
//
#include <hip/hip_runtime.h>
#include <hip/hip_bf16.h>
#include <math.h>

#define T_TRACKS 1024
#define HIDDEN 128
#define LATENT 16
#define NGRID 16
#define NCELLS 256
#define KDIM 4096
#define OUTD 128

typedef unsigned short ushort_t;
typedef __attribute__((ext_vector_type(8))) short frag_ab;   // 8 bf16
typedef __attribute__((ext_vector_type(4))) float f32x4;

static __device__ inline ushort_t f2bf(float x) {
    __hip_bfloat16 h = __float2bfloat16(x);
    return *reinterpret_cast<ushort_t*>(&h);
}

// ---------------- ws layout (byte offsets) ----------------
// vals_t bf16 [16 l][1024 j]      @ 0         (32 KB)
// owner u16 [1024 i][256 c]       @ 32768     (512 KB)  winner j+1, 0 = empty/invalid
// W_t bf16 [128 o][4096 k]        @ 557056    (1 MB)
// partial f32 [16 kt][1024][128]  @ 1605632   (8 MB)
#define WS_VALS 0
#define WS_OWN  32768
#define WS_WT   557056
#define WS_PART 1605632
#define WS_NEED (1605632 + 8388608)

// ============ K1: fused prep (vals_t | W_t transpose | owner map) ============
// logic verified in rounds 1-3.
__global__ __launch_bounds__(256) void prep_kernel(const float* __restrict__ hidden,
                                                   const float* __restrict__ obs2,
                                                   const float* __restrict__ W_enc,
                                                   const float* __restrict__ b_enc,
                                                   const float* __restrict__ W_emb,
                                                   ushort_t* __restrict__ vals_t,
                                                   ushort_t* __restrict__ owner,
                                                   ushort_t* __restrict__ W_t) {
    const int b = blockIdx.x;
    const int tid = threadIdx.x;
    if (b < 64) {
        // vals_t[l][j] = bf16(hidden[j] @ W_enc[:,l] + b_enc[l])
        int idx = b * 256 + tid;           // 0..16383
        int j = idx >> 4, l = idx & 15;
        const float* h = hidden + j * HIDDEN;
        float acc = b_enc[l];
#pragma unroll 8
        for (int k = 0; k < HIDDEN; k++) acc += h[k] * W_enc[k * LATENT + l];
        vals_t[l * T_TRACKS + j] = f2bf(acc);
    } else if (b < 320) {
        // W_t[o][k] = bf16(W_emb[k][o])
        int idx = (b - 64) * 256 + tid;    // 0..65535
        int kc = idx >> 7;                 // 0..511 (chunk of 8 k)
        int o = idx & 127;
        ushort_t tmp[8];
#pragma unroll
        for (int u = 0; u < 8; u++) tmp[u] = f2bf(W_emb[(kc * 8 + u) * OUTD + o]);
        *reinterpret_cast<uint4*>(W_t + o * KDIM + kc * 8) = *reinterpret_cast<uint4*>(tmp);
    } else {
        // owner map for 16 rows (winner = max j; ref's .set last-write = max j)
        __shared__ float2 sobs[T_TRACKS];      // 8 KB
        __shared__ int own[16][NCELLS];        // 16 KB
        const int rbase = (b - 320) * 16;
        for (int q = tid; q < T_TRACKS; q += 256) {
            float2 o = reinterpret_cast<const float2*>(obs2)[q];
            if (isnan(o.x) || isnan(o.y)) { o.x = 0.0f; o.y = 0.0f; }
            sobs[q] = o;
        }
        for (int q = tid; q < 16 * NCELLS; q += 256) (&own[0][0])[q] = -1;
        __syncthreads();
        {
            const int r = tid & 15;
            const int i = rbase + r;
            const float oix = sobs[i].x, oiy = sobs[i].y;
            for (int j = tid >> 4; j < T_TRACKS; j += 16) {
                if (j == i) continue;
                float gx = (sobs[j].x - oix) * 0.5f + 8.0f;
                float gy = (sobs[j].y - oiy) * 0.5f + 8.0f;
                bool inr = (gx >= 0.0f) && (gx < 16.0f) && (gy >= 0.0f) && (gy < 16.0f);
                int c = inr ? ((int)gx * NGRID + (int)gy) : 0;  // OOR scatters 0 into cell 0
                atomicMax(&own[r][c], j);
            }
        }
        __syncthreads();
        for (int q = tid; q < 16 * NCELLS; q += 256) {
            int rr = q >> 8, c = q & 255;
            int j = own[rr][c];
            bool valid = (j >= 0);
            if (valid && c == 0) {
                // cell 0's winner may be an out-of-range neighbor (value 0 in ref)
                float oix = sobs[rbase + rr].x, oiy = sobs[rbase + rr].y;
                float gx = (sobs[j].x - oix) * 0.5f + 8.0f;
                float gy = (sobs[j].y - oiy) * 0.5f + 8.0f;
                valid = (gx >= 0.0f) && (gx < 16.0f) && (gy >= 0.0f) && (gy < 16.0f);
            }
            owner[(rbase + rr) * NCELLS + c] = valid ? (ushort_t)(j + 1) : (ushort_t)0;
        }
    }
}

// ============ K2: GEMM (1024 blocks, 4/CU), plain partial stores — NO fences ============
// kt = b>>6 (K-seg == latent kt), mt = b&63 (16-row M-tile).
// Fragment/gather logic correctness-verified in rounds 2-3; round-3's decoupled
// tail removed: per-block agent-scope __threadfence costs ~1 µs serialized per
// XCD (measured: 120 µs @ 1024 blocks, all pipes idle) — never fence per-block.
__global__ __launch_bounds__(256, 4) void gemm_kernel(const ushort_t* __restrict__ owner,
                                                      const ushort_t* __restrict__ vals_t,
                                                      const ushort_t* __restrict__ W_t,
                                                      float* __restrict__ partial) {
    const int tid = threadIdx.x;
    const int kt = blockIdx.x >> 6;    // 0..15 (K-seg == latent kt)
    const int mt = blockIdx.x & 63;    // 0..63 (rows mt*16 .. +16)
    const int wave = tid >> 6;
    const int lane = tid & 63;
    const int lrow = lane & 15;
    const int quad = lane >> 4;

    __shared__ ushort_t As[16 * 136];     // 4352 B
    __shared__ ushort_t Bs[128 * 136];    // 34816 B  (total 39168 -> 4 blocks/CU)

    const ushort_t* vrow = vals_t + kt * T_TRACKS;   // 2 KB, L1-resident

    f32x4 acc[2];
    acc[0] = (f32x4){0.f, 0.f, 0.f, 0.f};
    acc[1] = (f32x4){0.f, 0.f, 0.f, 0.f};

    for (int chunk = 0; chunk < 2; chunk++) {
        const int c0 = chunk * 128;
        // A: 16 rows x 128 cells = 512 ushort4-quads, 2/thread (gather from owner+vrow)
        for (int q = tid; q < 512; q += 256) {
            int r = q >> 5, c4 = (q & 31) * 4;
            ushort4 o4 = *reinterpret_cast<const ushort4*>(owner + (mt * 16 + r) * NCELLS + c0 + c4);
            ushort4 v;
            v.x = o4.x ? vrow[o4.x - 1] : (ushort_t)0;
            v.y = o4.y ? vrow[o4.y - 1] : (ushort_t)0;
            v.z = o4.z ? vrow[o4.z - 1] : (ushort_t)0;
            v.w = o4.w ? vrow[o4.w - 1] : (ushort_t)0;
            *reinterpret_cast<ushort4*>(As + r * 136 + c4) = v;
        }
        // B: 128 n-rows x 128 k = 2048 16B-granules, 8/thread
        for (int g = tid; g < 2048; g += 256) {
            int n = g >> 4, cs = g & 15;
            uint4 v = *reinterpret_cast<const uint4*>(W_t + n * KDIM + kt * 256 + c0 + cs * 8);
            *reinterpret_cast<uint4*>(Bs + n * 136 + cs * 8) = v;
        }
        __syncthreads();
#pragma unroll
        for (int ks = 0; ks < 4; ks++) {   // K=32 per mfma
            const int koff = ks * 32 + quad * 8;
            frag_ab a = *reinterpret_cast<const frag_ab*>(&As[lrow * 136 + koff]);
#pragma unroll
            for (int nt2 = 0; nt2 < 2; nt2++) {
                int nrow = (wave * 2 + nt2) * 16 + lrow;
                frag_ab bfr = *reinterpret_cast<const frag_ab*>(&Bs[nrow * 136 + koff]);
                acc[nt2] = __builtin_amdgcn_mfma_f32_16x16x32_bf16(a, bfr, acc[nt2], 0, 0, 0);
            }
        }
        __syncthreads();
    }
    // C/D layout: col = lane&15, row = quad*4+reg (m89/m91-verified)
    float* pt = partial + (size_t)kt * (T_TRACKS * OUTD) + (mt * 16) * OUTD;
#pragma unroll
    for (int nt2 = 0; nt2 < 2; nt2++) {
        int n = (wave * 2 + nt2) * 16 + lrow;
#pragma unroll
        for (int reg = 0; reg < 4; reg++) {
            int m = quad * 4 + reg;
            pt[m * OUTD + n] = acc[nt2][reg];
        }
    }
}

// ============ K3: reduce 16 partials + bias + relu (round-0 verified) ============
__global__ __launch_bounds__(256) void reduce_kernel(const float* __restrict__ partial,
                                                     const float* __restrict__ b_emb,
                                                     float* __restrict__ out) {
    int idx = blockIdx.x * 256 + threadIdx.x;   // 0..32767 (float4 groups of [1024][128])
    const float4* p4 = reinterpret_cast<const float4*>(partial);
    float4 s = p4[idx];
#pragma unroll
    for (int kt = 1; kt < 16; kt++) {
        float4 v = p4[kt * 32768 + idx];
        s.x += v.x; s.y += v.y; s.z += v.z; s.w += v.w;
    }
    float4 bv = reinterpret_cast<const float4*>(b_emb)[idx & 31];
    float4 r;
    r.x = fmaxf(s.x + bv.x, 0.0f);
    r.y = fmaxf(s.y + bv.y, 0.0f);
    r.z = fmaxf(s.z + bv.z, 0.0f);
    r.w = fmaxf(s.w + bv.w, 0.0f);
    reinterpret_cast<float4*>(out)[idx] = r;
}

// ================= tiny-ws fallback (f32, fused, round-1 verified) =================
__global__ __launch_bounds__(256) void vals_kernel_f32(const float* __restrict__ hidden,
                                                       const float* __restrict__ W_enc,
                                                       const float* __restrict__ b_enc,
                                                       float* __restrict__ vals) {
    int idx = blockIdx.x * 256 + threadIdx.x;
    int j = idx >> 4, l = idx & 15;
    const float* h = hidden + j * HIDDEN;
    float acc = b_enc[l];
#pragma unroll 8
    for (int k = 0; k < HIDDEN; k++) acc += h[k] * W_enc[k * LATENT + l];
    vals[idx] = acc;
}

__global__ __launch_bounds__(256) void pool_kernel_f32(const float* __restrict__ obs2,
                                                       const float* __restrict__ vals,
                                                       const float* __restrict__ W_emb,
                                                       const float* __restrict__ b_emb,
                                                       float* __restrict__ out) {
    const int i = blockIdx.x;
    const int tid = threadIdx.x;
    __shared__ int owner[NCELLS];
    __shared__ float occ[NCELLS * LATENT];
    __shared__ float partial[OUTD];
    owner[tid] = -1;
    float oix = obs2[i * 2 + 0];
    float oiy = obs2[i * 2 + 1];
    if (isnan(oix) || isnan(oiy)) { oix = 0.0f; oiy = 0.0f; }
    __syncthreads();
    for (int j = tid; j < T_TRACKS; j += 256) {
        if (j == i) continue;
        float ox = obs2[j * 2 + 0], oy = obs2[j * 2 + 1];
        if (isnan(ox) || isnan(oy)) { ox = 0.0f; oy = 0.0f; }
        float gx = (ox - oix) * 0.5f + 8.0f;
        float gy = (oy - oiy) * 0.5f + 8.0f;
        bool inr = (gx >= 0.0f) && (gx < 16.0f) && (gy >= 0.0f) && (gy < 16.0f);
        int c = inr ? ((int)gx * NGRID + (int)gy) : 0;
        atomicMax(&owner[c], j);
    }
    __syncthreads();
    {
        int j = owner[tid];
        bool valid = false;
        if (j >= 0) {
            float ox = obs2[j * 2 + 0], oy = obs2[j * 2 + 1];
            if (isnan(ox) || isnan(oy)) { ox = 0.0f; oy = 0.0f; }
            float gx = (ox - oix) * 0.5f + 8.0f;
            float gy = (oy - oiy) * 0.5f + 8.0f;
            valid = (gx >= 0.0f) && (gx < 16.0f) && (gy >= 0.0f) && (gy < 16.0f);
        }
        const float* vj = vals + (j >= 0 ? j : 0) * LATENT;
#pragma unroll
        for (int l = 0; l < LATENT; l++) occ[tid * LATENT + l] = valid ? vj[l] : 0.0f;
    }
    __syncthreads();
    const int o = tid & (OUTD - 1);
    const int half = tid >> 7;
    const int cbase = half * 128;
    float acc = 0.0f;
    for (int c = cbase; c < cbase + 128; c++) {
#pragma unroll
        for (int l = 0; l < LATENT; l++)
            acc += occ[c * LATENT + l] * W_emb[(l * NCELLS + c) * OUTD + o];
    }
    if (half == 0) partial[o] = acc;
    __syncthreads();
    if (half == 1) out[i * OUTD + o] = fmaxf(acc + partial[o] + b_emb[o], 0.0f);
}

extern "C" void kernel_launch(void* const* d_in, const int* in_sizes, int n_in,
                              void* d_out, int out_size, void* d_ws, size_t ws_size,
                              hipStream_t stream) {
    const float* hidden = (const float*)d_in[0];   // [1024,128]
    const float* obs2   = (const float*)d_in[2];   // [1024,2]
    const float* W_enc  = (const float*)d_in[3];   // [128,16]
    const float* b_enc  = (const float*)d_in[4];   // [16]
    const float* W_emb  = (const float*)d_in[5];   // [4096,128]
    const float* b_emb  = (const float*)d_in[6];   // [128]
    float* out = (float*)d_out;                    // [1024,128]

    if (ws_size < (size_t)WS_NEED) {
        float* vals = (float*)d_ws;
        vals_kernel_f32<<<(T_TRACKS * LATENT) / 256, 256, 0, stream>>>(hidden, W_enc, b_enc, vals);
        pool_kernel_f32<<<T_TRACKS, 256, 0, stream>>>(obs2, vals, W_emb, b_emb, out);
        return;
    }

    char* ws = (char*)d_ws;
    ushort_t* vals_t  = (ushort_t*)(ws + WS_VALS);
    ushort_t* owner   = (ushort_t*)(ws + WS_OWN);
    ushort_t* W_t     = (ushort_t*)(ws + WS_WT);
    float*    partial = (float*)(ws + WS_PART);

    prep_kernel<<<384, 256, 0, stream>>>(hidden, obs2, W_enc, b_enc, W_emb,
                                         vals_t, owner, W_t);
    gemm_kernel<<<1024, 256, 0, stream>>>(owner, vals_t, W_t, partial);
    reduce_kernel<<<128, 256, 0, stream>>>(partial, b_emb, out);
}

// Round 5
// 91.138 us; speedup vs baseline: 3.6059x; 1.0298x over previous
//
#include <hip/hip_runtime.h>
#include <hip/hip_bf16.h>
#include <math.h>

#define T_TRACKS 1024
#define HIDDEN 128
#define LATENT 16
#define NGRID 16
#define NCELLS 256
#define KDIM 4096
#define OUTD 128

typedef unsigned short ushort_t;
typedef __attribute__((ext_vector_type(8))) short frag_ab;   // 8 bf16
typedef __attribute__((ext_vector_type(4))) float f32x4;

static __device__ inline ushort_t f2bf(float x) {
    __hip_bfloat16 h = __float2bfloat16(x);
    return *reinterpret_cast<ushort_t*>(&h);
}

// ---------------- ws layout (byte offsets) ----------------
// vals_bf16 [1024][16]             @ 0         (32 KB)
// W_t bf16 [128 o][4096 k]         @ 32768     (1 MB)
// occ bf16 [1024][4096]            @ 1081344   (8 MB)
// partial f32 [16 kt][1024][128]   @ 9469952   (8 MB)
#define WS_VALS 0
#define WS_WT   32768
#define WS_OCC  1081344
#define WS_PART 9469952
#define WS_NEED (9469952 + 8388608)

// ============ K1: prep (vals bf16 | W_emb transpose->bf16) ============
__global__ __launch_bounds__(256) void prep_kernel(const float* __restrict__ hidden,
                                                   const float* __restrict__ W_enc,
                                                   const float* __restrict__ b_enc,
                                                   const float* __restrict__ W_emb,
                                                   ushort_t* __restrict__ vals_bf16,
                                                   ushort_t* __restrict__ W_t) {
    const int b = blockIdx.x;
    const int tid = threadIdx.x;
    if (b < 64) {
        // vals[j][l] = hidden[j] @ W_enc[:,l] + b_enc[l]  -> bf16
        int idx = b * 256 + tid;           // 0..16383
        int j = idx >> 4, l = idx & 15;
        const float* h = hidden + j * HIDDEN;
        float acc = b_enc[l];
#pragma unroll 8
        for (int k = 0; k < HIDDEN; k++) acc += h[k] * W_enc[k * LATENT + l];
        vals_bf16[idx] = f2bf(acc);
    } else {
        // W_t[o][k] = bf16(W_emb[k][o]); thread handles (o, 8 consecutive k)
        int idx = (b - 64) * 256 + tid;    // 0..65535
        int kc = idx >> 7;                 // 0..511 (chunk of 8 k)
        int o = idx & 127;
        ushort_t tmp[8];
#pragma unroll
        for (int u = 0; u < 8; u++) tmp[u] = f2bf(W_emb[(kc * 8 + u) * OUTD + o]);
        *reinterpret_cast<uint4*>(W_t + o * KDIM + kc * 8) = *reinterpret_cast<uint4*>(tmp);
    }
}

// ============ K2: build occ rows (bf16, k = l*256 + c order) ============
// Thread t == cell c: winner's 16 latents read as one contiguous 32B load,
// transposed through LDS, then 8KB row stored coalesced.
__global__ __launch_bounds__(256) void occ_kernel(const float* __restrict__ obs2,
                                                  const ushort_t* __restrict__ vals_bf16,
                                                  ushort_t* __restrict__ occ) {
    const int i = blockIdx.x;
    const int tid = threadIdx.x;
    __shared__ int owner[NCELLS];
    __shared__ ushort_t socc[LATENT * NCELLS];   // [l][c], 8 KB
    owner[tid] = -1;

    float oix = obs2[i * 2 + 0];
    float oiy = obs2[i * 2 + 1];
    if (isnan(oix) || isnan(oiy)) { oix = 0.0f; oiy = 0.0f; }
    __syncthreads();

    for (int j = tid; j < T_TRACKS; j += 256) {
        if (j == i) continue;
        float ox = obs2[j * 2 + 0];
        float oy = obs2[j * 2 + 1];
        if (isnan(ox) || isnan(oy)) { ox = 0.0f; oy = 0.0f; }
        float gx = (ox - oix) * 0.5f + 8.0f;
        float gy = (oy - oiy) * 0.5f + 8.0f;
        bool inr = (gx >= 0.0f) && (gx < 16.0f) && (gy >= 0.0f) && (gy < 16.0f);
        int c = inr ? ((int)gx * NGRID + (int)gy) : 0;   // OOR scatters 0 into cell 0
        atomicMax(&owner[c], j);
    }
    __syncthreads();

    {
        const int c = tid;
        int j = owner[c];
        bool valid = (j >= 0);
        if (c == 0 && valid) {
            // cell 0's winner may be an out-of-range neighbor (value 0)
            float ox = obs2[j * 2 + 0];
            float oy = obs2[j * 2 + 1];
            if (isnan(ox) || isnan(oy)) { ox = 0.0f; oy = 0.0f; }
            float gx = (ox - oix) * 0.5f + 8.0f;
            float gy = (oy - oiy) * 0.5f + 8.0f;
            valid = (gx >= 0.0f) && (gx < 16.0f) && (gy >= 0.0f) && (gy < 16.0f);
        }
        int jj = (j >= 0) ? j : 0;
        ushort_t vv[16];
        *reinterpret_cast<uint4*>(vv)     = *reinterpret_cast<const uint4*>(vals_bf16 + jj * LATENT);
        *reinterpret_cast<uint4*>(vv + 8) = *reinterpret_cast<const uint4*>(vals_bf16 + jj * LATENT + 8);
#pragma unroll
        for (int l = 0; l < LATENT; l++) {
            socc[l * NCELLS + c] = valid ? vv[l] : (ushort_t)0;
        }
    }
    __syncthreads();

    // coalesced store of the 4096-elem row (512 uint4, 2 per thread)
    uint4* dst = reinterpret_cast<uint4*>(occ + i * KDIM);
    const uint4* src = reinterpret_cast<const uint4*>(socc);
    dst[tid]       = src[tid];
    dst[tid + 256] = src[tid + 256];
}

// ============ K3: MFMA GEMM, K-split partials (no atomics) ============
// grid = 256: kt = blockIdx & 15 (Kseg=256), mt = blockIdx >> 4 (Mtile=64)
#define BK 128
#define LDSTR 136   // row stride in bf16 elems (128 + 8 pad)
__global__ __launch_bounds__(256) void gemm_kernel(const ushort_t* __restrict__ occ,
                                                   const ushort_t* __restrict__ W_t,
                                                   float* __restrict__ partial) {
    const int tid = threadIdx.x;
    const int kt = blockIdx.x & 15;
    const int mt = blockIdx.x >> 4;
    const int wave = tid >> 6;
    const int lane = tid & 63;
    const int lrow = lane & 15;
    const int quad = lane >> 4;

    __shared__ ushort_t As[64 * LDSTR];    // 17408 B
    __shared__ ushort_t Bs[128 * LDSTR];   // 34816 B

    f32x4 acc[8];
#pragma unroll
    for (int nt = 0; nt < 8; nt++) acc[nt] = (f32x4){0.f, 0.f, 0.f, 0.f};

    for (int chunk = 0; chunk < 2; chunk++) {
        const int k0 = kt * 256 + chunk * BK;
        // stage A: 64 rows x 128 k = 1024 16B-granules
        for (int g = tid; g < 1024; g += 256) {
            int r = g >> 4, cs = g & 15;
            uint4 v = *reinterpret_cast<const uint4*>(occ + (mt * 64 + r) * KDIM + k0 + cs * 8);
            *reinterpret_cast<uint4*>(As + r * LDSTR + cs * 8) = v;
        }
        // stage B: 128 rows x 128 k = 2048 granules
        for (int g = tid; g < 2048; g += 256) {
            int n = g >> 4, cs = g & 15;
            uint4 v = *reinterpret_cast<const uint4*>(W_t + n * KDIM + k0 + cs * 8);
            *reinterpret_cast<uint4*>(Bs + n * LDSTR + cs * 8) = v;
        }
        __syncthreads();
#pragma unroll
        for (int ks = 0; ks < 4; ks++) {   // K=32 per mfma
            const int koff = ks * 32 + quad * 8;
            frag_ab a = *reinterpret_cast<const frag_ab*>(&As[(wave * 16 + lrow) * LDSTR + koff]);
#pragma unroll
            for (int nt = 0; nt < 8; nt++) {
                frag_ab bfr = *reinterpret_cast<const frag_ab*>(&Bs[(nt * 16 + lrow) * LDSTR + koff]);
                acc[nt] = __builtin_amdgcn_mfma_f32_16x16x32_bf16(a, bfr, acc[nt], 0, 0, 0);
            }
        }
        __syncthreads();
    }
    // C/D layout: col = lane&15, row = quad*4+reg (m89/m91-verified).
    // Plain stores into this block's private partial tile.
    float* pt = partial + (size_t)kt * (T_TRACKS * OUTD) + (mt * 64) * OUTD;
#pragma unroll
    for (int nt = 0; nt < 8; nt++) {
        int n = nt * 16 + lrow;
#pragma unroll
        for (int reg = 0; reg < 4; reg++) {
            int m = wave * 16 + quad * 4 + reg;
            pt[m * OUTD + n] = acc[nt][reg];
        }
    }
}

// ============ K4: reduce 16 partials + bias + relu ============
__global__ __launch_bounds__(256) void reduce_kernel(const float* __restrict__ partial,
                                                     const float* __restrict__ b_emb,
                                                     float* __restrict__ out) {
    int idx = blockIdx.x * 256 + threadIdx.x;   // 0..32767 (float4 groups of [1024][128])
    const float4* p4 = reinterpret_cast<const float4*>(partial);
    float4 s = p4[idx];
#pragma unroll
    for (int kt = 1; kt < 16; kt++) {
        float4 v = p4[kt * 32768 + idx];
        s.x += v.x; s.y += v.y; s.z += v.z; s.w += v.w;
    }
    float4 bv = reinterpret_cast<const float4*>(b_emb)[idx & 31];
    float4 r;
    r.x = fmaxf(s.x + bv.x, 0.0f);
    r.y = fmaxf(s.y + bv.y, 0.0f);
    r.z = fmaxf(s.z + bv.z, 0.0f);
    r.w = fmaxf(s.w + bv.w, 0.0f);
    reinterpret_cast<float4*>(out)[idx] = r;
}

// ================= Round-1 fallback (f32, fused) for small ws =================
__global__ __launch_bounds__(256) void vals_kernel_f32(const float* __restrict__ hidden,
                                                       const float* __restrict__ W_enc,
                                                       const float* __restrict__ b_enc,
                                                       float* __restrict__ vals) {
    int idx = blockIdx.x * 256 + threadIdx.x;
    int j = idx >> 4, l = idx & 15;
    const float* h = hidden + j * HIDDEN;
    float acc = b_enc[l];
#pragma unroll 8
    for (int k = 0; k < HIDDEN; k++) acc += h[k] * W_enc[k * LATENT + l];
    vals[idx] = acc;
}

__global__ __launch_bounds__(256) void pool_kernel_f32(const float* __restrict__ obs2,
                                                       const float* __restrict__ vals,
                                                       const float* __restrict__ W_emb,
                                                       const float* __restrict__ b_emb,
                                                       float* __restrict__ out) {
    const int i = blockIdx.x;
    const int tid = threadIdx.x;
    __shared__ int owner[NCELLS];
    __shared__ float occ[NCELLS * LATENT];
    __shared__ float partial[OUTD];
    owner[tid] = -1;
    float oix = obs2[i * 2 + 0];
    float oiy = obs2[i * 2 + 1];
    if (isnan(oix) || isnan(oiy)) { oix = 0.0f; oiy = 0.0f; }
    __syncthreads();
    for (int j = tid; j < T_TRACKS; j += 256) {
        if (j == i) continue;
        float ox = obs2[j * 2 + 0], oy = obs2[j * 2 + 1];
        if (isnan(ox) || isnan(oy)) { ox = 0.0f; oy = 0.0f; }
        float gx = (ox - oix) * 0.5f + 8.0f;
        float gy = (oy - oiy) * 0.5f + 8.0f;
        bool inr = (gx >= 0.0f) && (gx < 16.0f) && (gy >= 0.0f) && (gy < 16.0f);
        int c = inr ? ((int)gx * NGRID + (int)gy) : 0;
        atomicMax(&owner[c], j);
    }
    __syncthreads();
    {
        int j = owner[tid];
        bool valid = false;
        if (j >= 0) {
            float ox = obs2[j * 2 + 0], oy = obs2[j * 2 + 1];
            if (isnan(ox) || isnan(oy)) { ox = 0.0f; oy = 0.0f; }
            float gx = (ox - oix) * 0.5f + 8.0f;
            float gy = (oy - oiy) * 0.5f + 8.0f;
            valid = (gx >= 0.0f) && (gx < 16.0f) && (gy >= 0.0f) && (gy < 16.0f);
        }
        const float* vj = vals + (j >= 0 ? j : 0) * LATENT;
#pragma unroll
        for (int l = 0; l < LATENT; l++) occ[tid * LATENT + l] = valid ? vj[l] : 0.0f;
    }
    __syncthreads();
    const int o = tid & (OUTD - 1);
    const int half = tid >> 7;
    const int cbase = half * 128;
    float acc = 0.0f;
    for (int c = cbase; c < cbase + 128; c++) {
#pragma unroll
        for (int l = 0; l < LATENT; l++)
            acc += occ[c * LATENT + l] * W_emb[(l * NCELLS + c) * OUTD + o];
    }
    if (half == 0) partial[o] = acc;
    __syncthreads();
    if (half == 1) out[i * OUTD + o] = fmaxf(acc + partial[o] + b_emb[o], 0.0f);
}

extern "C" void kernel_launch(void* const* d_in, const int* in_sizes, int n_in,
                              void* d_out, int out_size, void* d_ws, size_t ws_size,
                              hipStream_t stream) {
    const float* hidden = (const float*)d_in[0];   // [1024,128]
    const float* obs2   = (const float*)d_in[2];   // [1024,2]
    const float* W_enc  = (const float*)d_in[3];   // [128,16]
    const float* b_enc  = (const float*)d_in[4];   // [16]
    const float* W_emb  = (const float*)d_in[5];   // [4096,128]
    const float* b_emb  = (const float*)d_in[6];   // [128]
    float* out = (float*)d_out;                    // [1024,128]

    if (ws_size < (size_t)WS_NEED) {
        // fallback: round-1 verified f32 path
        float* vals = (float*)d_ws;
        vals_kernel_f32<<<(T_TRACKS * LATENT) / 256, 256, 0, stream>>>(hidden, W_enc, b_enc, vals);
        pool_kernel_f32<<<T_TRACKS, 256, 0, stream>>>(obs2, vals, W_emb, b_emb, out);
        return;
    }

    char* ws = (char*)d_ws;
    ushort_t* vals_bf16 = (ushort_t*)(ws + WS_VALS);
    ushort_t* W_t       = (ushort_t*)(ws + WS_WT);
    ushort_t* occ       = (ushort_t*)(ws + WS_OCC);
    float*    partial   = (float*)(ws + WS_PART);

    prep_kernel<<<320, 256, 0, stream>>>(hidden, W_enc, b_enc, W_emb, vals_bf16, W_t);
    occ_kernel<<<T_TRACKS, 256, 0, stream>>>(obs2, vals_bf16, occ);
    gemm_kernel<<<256, 256, 0, stream>>>(occ, W_t, partial);
    reduce_kernel<<<128, 256, 0, stream>>>(partial, b_emb, out);
}